// Round 7
// baseline (1017.248 us; speedup 1.0000x reference)
//
#include <hip/hip_runtime.h>
#include <hip/hip_bf16.h>
#include <stdint.h>

namespace {

constexpr int Hh    = 16;
constexpr int LL    = 4096;
constexpr int DD    = 64;
constexpr int BH    = 64;            // B*H
constexpr int CHUNK = 128;           // rows per block
constexpr int NCH   = LL / CHUNK;    // 32 chunks per (b,h)
constexpr int RPT   = 8;             // rows per 16-lane team
constexpr int RECF  = 128;           // floats per record (64 k-sums | 64 kv-sums)
constexpr int NBLK  = BH * NCH;      // 2048
constexpr float EPS = 1e-6f;

typedef __attribute__((ext_vector_type(4))) float f32x4;

__device__ __forceinline__ float elu1(float x) {
    return x > 0.0f ? x + 1.0f : __expf(x);
}

// --- 16-lane team butterfly sum (teams are 16-lane aligned within the wave) ---
template<int CTRL>
__device__ __forceinline__ float dpp_xor_add(float x) {
    int yi = __builtin_amdgcn_update_dpp(0, __float_as_int(x), CTRL, 0xF, 0xF, true);
    return x + __int_as_float(yi);
}
template<int IMM>
__device__ __forceinline__ float swz_xor_add(float x) {
    int yi = __builtin_amdgcn_ds_swizzle(__float_as_int(x), IMM);
    return x + __int_as_float(yi);
}
__device__ __forceinline__ float team_sum16(float x) {
    x = dpp_xor_add<0xB1>(x);      // quad_perm xor 1
    x = dpp_xor_add<0x4E>(x);      // quad_perm xor 2
    x = swz_xor_add<0x101F>(x);    // ds_swizzle xor 4
    x = swz_xor_add<0x201F>(x);    // ds_swizzle xor 8
    return x;
}

__device__ __forceinline__ float4 f4add(float4 a, float4 b) {
    return make_float4(a.x + b.x, a.y + b.y, a.z + b.z, a.w + b.w);
}

// ============================================================================
// Single fused kernel: ticket-chained inclusive scan of chunk totals.
// Work assignment by ticket (NOT blockIdx): guarantees the predecessor of any
// waiting block already holds a smaller ticket => resident or finished => no
// deadlock. Record math is fixed-order => bitwise deterministic.
// ============================================================================
__global__ __launch_bounds__(256) void la_fused(
    const float* __restrict__ qp, const float* __restrict__ kp,
    const float* __restrict__ vp, const float* __restrict__ maskp,
    uint32_t* __restrict__ counter, uint32_t* __restrict__ flags,
    float* __restrict__ records, float* __restrict__ outp)
{
    const int t    = threadIdx.x;
    const int qd   = t & 15;
    const int team = t >> 4;

    // ---- ticket ----
    __shared__ uint32_t s_vb;
    if (t == 0)
        s_vb = __hip_atomic_fetch_add(counter, 1u, __ATOMIC_RELAXED,
                                      __HIP_MEMORY_SCOPE_AGENT);
    __syncthreads();
    const int vb = (int)s_vb;
    const int bh = vb >> 5;          // / NCH
    const int ch = vb & (NCH - 1);
    const int b  = bh >> 4;          // / Hh

    const long base  = ((long)bh * LL + (long)ch * CHUNK) * DD;
    const long rbase = base + (long)team * RPT * DD + qd * 4;
    const float* mrow = maskp + (long)b * LL + (long)ch * CHUNK + team * RPT;

    // ---- k/v tile burst (R6 pass2 shape) ----
    float4 kb[RPT], vv[RPT];
    float  mv[RPT];
    #pragma unroll
    for (int r = 0; r < RPT; ++r) {
        kb[r] = *(const float4*)(kp + rbase + (long)r * DD);
        vv[r] = *(const float4*)(vp + rbase + (long)r * DD);
        mv[r] = mrow[r];
    }

    // ---- transform in place: kb <- kf = elu1(k)*m, vv <- kv = kf*(v*m) ----
    #pragma unroll
    for (int r = 0; r < RPT; ++r) {
        const float m = mv[r];
        float4 f;
        f.x = elu1(kb[r].x) * m; f.y = elu1(kb[r].y) * m;
        f.z = elu1(kb[r].z) * m; f.w = elu1(kb[r].w) * m;
        float4 g;
        g.x = f.x * (vv[r].x * m); g.y = f.y * (vv[r].y * m);
        g.z = f.z * (vv[r].z * m); g.w = f.w * (vv[r].w * m);
        kb[r] = f;
        vv[r] = g;
    }

    // ---- team totals ----
    float4 tk = make_float4(0.f, 0.f, 0.f, 0.f);
    float4 tv = make_float4(0.f, 0.f, 0.f, 0.f);
    #pragma unroll
    for (int r = 0; r < RPT; ++r) { tk = f4add(tk, kb[r]); tv = f4add(tv, vv[r]); }

    __shared__ float red[16][RECF];
    __shared__ float pre[16][RECF];
    __shared__ float carry_lds[RECF];
    red[team][qd*4+0] = tk.x; red[team][qd*4+1] = tk.y;
    red[team][qd*4+2] = tk.z; red[team][qd*4+3] = tk.w;
    red[team][64+qd*4+0] = tv.x; red[team][64+qd*4+1] = tv.y;
    red[team][64+qd*4+2] = tv.z; red[team][64+qd*4+3] = tv.w;

    // ---- q burst issued early: drains under the scan + chain wait ----
    float4 qb[RPT];
    #pragma unroll
    for (int r = 0; r < RPT; ++r)
        qb[r] = *(const float4*)(qp + rbase + (long)r * DD);

    __syncthreads();

    // ---- in-block exclusive scan over teams; acc = chunk total (t<128) ----
    float acc = 0.f;
    if (t < RECF) {
        #pragma unroll
        for (int i = 0; i < 16; ++i) { pre[i][t] = acc; acc += red[i][t]; }
    }

    // ---- chain: wait for predecessor chunk's inclusive record ----
    if (ch > 0 && t == 0) {
        while (__hip_atomic_load(&flags[vb - 1], __ATOMIC_ACQUIRE,
                                 __HIP_MEMORY_SCOPE_AGENT) == 0u)
            __builtin_amdgcn_s_sleep(16);
    }
    __syncthreads();

    float carry = 0.f;
    if (t < RECF) {
        if (ch > 0)
            carry = __hip_atomic_load(&records[(long)(vb - 1) * RECF + t],
                                      __ATOMIC_RELAXED, __HIP_MEMORY_SCOPE_AGENT);
        __hip_atomic_store(&records[(long)vb * RECF + t], carry + acc,
                           __ATOMIC_RELAXED, __HIP_MEMORY_SCOPE_AGENT);
        carry_lds[t] = carry;
    }
    __syncthreads();   // record stores drained (vmcnt(0) before barrier)
    if (t == 0) {
        __threadfence();
        __hip_atomic_store(&flags[vb], 1u, __ATOMIC_RELEASE,
                           __HIP_MEMORY_SCOPE_AGENT);
    }

    // ---- phase C: running state = carry + team prefix; serial 8-row scan ----
    float4 rk, rv;
    rk.x = carry_lds[qd*4+0] + pre[team][qd*4+0];
    rk.y = carry_lds[qd*4+1] + pre[team][qd*4+1];
    rk.z = carry_lds[qd*4+2] + pre[team][qd*4+2];
    rk.w = carry_lds[qd*4+3] + pre[team][qd*4+3];
    rv.x = carry_lds[64+qd*4+0] + pre[team][64+qd*4+0];
    rv.y = carry_lds[64+qd*4+1] + pre[team][64+qd*4+1];
    rv.z = carry_lds[64+qd*4+2] + pre[team][64+qd*4+2];
    rv.w = carry_lds[64+qd*4+3] + pre[team][64+qd*4+3];

    #pragma unroll
    for (int r = 0; r < RPT; ++r) {
        rk = f4add(rk, kb[r]);
        rv = f4add(rv, vv[r]);

        float4 qf;
        qf.x = elu1(qb[r].x); qf.y = elu1(qb[r].y);
        qf.z = elu1(qb[r].z); qf.w = elu1(qb[r].w);

        float pz = qf.x*rk.x + qf.y*rk.y + qf.z*rk.z + qf.w*rk.w;
        pz = team_sum16(pz);

        const float z   = (pz + EPS) * mv[r];
        const float inv = __builtin_amdgcn_rcpf(z);

        f32x4 o;
        o.x = qf.x * rv.x * inv;
        o.y = qf.y * rv.y * inv;
        o.z = qf.z * rv.z * inv;
        o.w = qf.w * rv.w * inv;
        __builtin_nontemporal_store(o, (f32x4*)(outp + rbase + (long)r * DD));
    }
}

} // namespace

extern "C" void kernel_launch(void* const* d_in, const int* in_sizes, int n_in,
                              void* d_out, int out_size, void* d_ws, size_t ws_size,
                              hipStream_t stream) {
    const float* q    = (const float*)d_in[0];
    const float* k    = (const float*)d_in[1];
    const float* v    = (const float*)d_in[2];
    const float* mask = (const float*)d_in[3];
    float* out = (float*)d_out;

    // ws layout: [0..4)   counter
    //            [256..256+NBLK*4)  flags
    //            [16384..16384+NBLK*RECF*4)  records (1 MiB)
    uint32_t* counter = (uint32_t*)d_ws;
    uint32_t* flags   = (uint32_t*)((char*)d_ws + 256);
    float*    records = (float*)((char*)d_ws + 16384);

    // zero counter + flags each call (graph-capturable)
    hipMemsetAsync(d_ws, 0, 16384, stream);

    la_fused<<<dim3(NBLK), dim3(256), 0, stream>>>(q, k, v, mask,
                                                   counter, flags, records, out);
}

// Round 9
// 66.020 us; speedup vs baseline: 15.4081x; 15.4081x over previous
//
#include <hip/hip_runtime.h>
#include <hip/hip_bf16.h>
#include <stdint.h>

namespace {

constexpr int Hh    = 16;
constexpr int LL    = 4096;
constexpr int DD    = 64;
constexpr int BH    = 64;            // B*H
constexpr int CHUNK = 128;           // rows per block
constexpr int NCH   = LL / CHUNK;    // 32 chunks per (b,h)
constexpr int RPT   = 8;             // rows per 16-lane team
constexpr int RECF  = 128;           // floats per ws record (64 k-sums | 64 kv-sums)
constexpr int TILEF = CHUNK * DD;    // 8192 floats per stream tile (32 KB)
constexpr float EPS = 1e-6f;

typedef __attribute__((ext_vector_type(4))) float f32x4;

__device__ __forceinline__ float elu1(float x) {
    return x > 0.0f ? x + 1.0f : __expf(x);
}

// --- 16-lane team butterfly sum ---
template<int CTRL>
__device__ __forceinline__ float dpp_xor_add(float x) {
    int yi = __builtin_amdgcn_update_dpp(0, __float_as_int(x), CTRL, 0xF, 0xF, true);
    return x + __int_as_float(yi);
}
template<int IMM>
__device__ __forceinline__ float swz_xor_add(float x) {
    int yi = __builtin_amdgcn_ds_swizzle(__float_as_int(x), IMM);
    return x + __int_as_float(yi);
}
__device__ __forceinline__ float team_sum16(float x) {
    x = dpp_xor_add<0xB1>(x);
    x = dpp_xor_add<0x4E>(x);
    x = swz_xor_add<0x101F>(x);
    x = swz_xor_add<0x201F>(x);
    return x;
}

// --- async global->LDS 16B: global src PER-LANE, LDS dest wave-uniform ---
typedef const __attribute__((address_space(1))) void* as1_t;
typedef __attribute__((address_space(3))) void* as3_t;
__device__ __forceinline__ void gload16(const void* g, void* l) {
    __builtin_amdgcn_global_load_lds((as1_t)g, (as3_t)l, 16, 0, 0);
}

// ============================================================================
// Pass 1: per-chunk (128-row) totals of kf and kf*vm -> ws[bh*NCH+ch][128]
// ============================================================================
__global__ __launch_bounds__(256) void la_pass1(
    const float* __restrict__ kp, const float* __restrict__ vp,
    const float* __restrict__ maskp, float* __restrict__ ws)
{
    const int blk  = blockIdx.x;
    const int bh   = blk >> 5;
    const int ch   = blk & (NCH - 1);
    const int b    = bh >> 4;
    const int t    = threadIdx.x;
    const int qd   = t & 15;
    const int team = t >> 4;

    const long base  = ((long)bh * LL + (long)ch * CHUNK) * DD;
    const long rbase = base + (long)team * RPT * DD + qd * 4;
    const float* mrow = maskp + (long)b * LL + (long)ch * CHUNK + team * RPT;

    float4 sk = make_float4(0.f, 0.f, 0.f, 0.f);
    float4 sv = make_float4(0.f, 0.f, 0.f, 0.f);

    #pragma unroll
    for (int r = 0; r < RPT; ++r) {
        const float4 k4 = *(const float4*)(kp + rbase + (long)r * DD);
        const float4 v4 = *(const float4*)(vp + rbase + (long)r * DD);
        const float  m  = mrow[r];
        const float kf0 = elu1(k4.x) * m;
        const float kf1 = elu1(k4.y) * m;
        const float kf2 = elu1(k4.z) * m;
        const float kf3 = elu1(k4.w) * m;
        sk.x += kf0;              sk.y += kf1;
        sk.z += kf2;              sk.w += kf3;
        sv.x += kf0 * (v4.x * m); sv.y += kf1 * (v4.y * m);
        sv.z += kf2 * (v4.z * m); sv.w += kf3 * (v4.w * m);
    }

    __shared__ float red[16][RECF];
    red[team][qd*4+0] = sk.x; red[team][qd*4+1] = sk.y;
    red[team][qd*4+2] = sk.z; red[team][qd*4+3] = sk.w;
    red[team][64+qd*4+0] = sv.x; red[team][64+qd*4+1] = sv.y;
    red[team][64+qd*4+2] = sv.z; red[team][64+qd*4+3] = sv.w;
    __syncthreads();

    if (t < RECF) {
        float acc = 0.f;
        #pragma unroll
        for (int i = 0; i < 16; ++i) acc += red[i][t];
        ws[((long)bh * NCH + ch) * RECF + t] = acc;
    }
}

// ============================================================================
// Pass 1.5: in-place exclusive scan of the NCH chunk-total records per (b,h).
// ============================================================================
__global__ __launch_bounds__(RECF) void la_scan(float* __restrict__ ws)
{
    const int bh = blockIdx.x;
    const int t  = threadIdx.x;
    float* wb = ws + (long)bh * NCH * RECF + t;

    float vals[NCH];
    #pragma unroll
    for (int c = 0; c < NCH; ++c) vals[c] = wb[(long)c * RECF];

    float acc = 0.f;
    #pragma unroll
    for (int c = 0; c < NCH; ++c) {
        const float x = vals[c];
        wb[(long)c * RECF] = acc;
        acc += x;
    }
}

// ============================================================================
// Pass 2: k,v chunk tiles DMA'd to LDS via global_load_lds (zero VGPR cost,
// 16 instrs/wave issued up-front, one drain). Phase B: team totals from LDS.
// In-place team scan. Phase C: re-read LDS, recompute elu, serial 8-row scan.
// q = register burst issued before the drain.
// LDS: 64 KB tile + 8 KB scan = 72 KB -> 2 blocks/CU.
// ============================================================================
__global__ __launch_bounds__(256) void la_pass2(
    const float* __restrict__ qp, const float* __restrict__ kp,
    const float* __restrict__ vp, const float* __restrict__ maskp,
    const float* __restrict__ ws, float* __restrict__ outp)
{
    const int blk  = blockIdx.x;
    const int bh   = blk >> 5;
    const int ch   = blk & (NCH - 1);
    const int b    = bh >> 4;
    const int t    = threadIdx.x;
    const int qd   = t & 15;
    const int team = t >> 4;
    const int wave = t >> 6;
    const int ln   = t & 63;

    const long base  = ((long)bh * LL + (long)ch * CHUNK) * DD;  // contig 8192-float tile
    const long rbase = base + (long)team * RPT * DD + qd * 4;
    const float* mrow = maskp + (long)b * LL + (long)ch * CHUNK + team * RPT;

    __shared__ __align__(16) float tileK[TILEF];
    __shared__ __align__(16) float tileV[TILEF];
    __shared__ float red[16][RECF];

    // ---- phase A: issue all DMA. global src = per-lane (ln*4 floats = 16 B),
    //      LDS dest = wave-uniform segment base (HW adds lane*16). ----
    {
        const int woff = wave * 256;              // floats, uniform per wave
        #pragma unroll
        for (int i = 0; i < 8; ++i)
            gload16(kp + base + i * 1024 + woff + ln * 4, &tileK[i * 1024 + woff]);
        #pragma unroll
        for (int i = 0; i < 8; ++i)
            gload16(vp + base + i * 1024 + woff + ln * 4, &tileV[i * 1024 + woff]);
    }

    // ---- carry record (512 B, L2-hot) + mask + q burst, drain under DMA ----
    const float* rec = ws + ((long)bh * NCH + ch) * RECF;
    const float4 ck = *(const float4*)(rec + qd * 4);
    const float4 cv = *(const float4*)(rec + 64 + qd * 4);

    float mv[RPT];
    #pragma unroll
    for (int r = 0; r < RPT; ++r) mv[r] = mrow[r];

    float4 qb[RPT];
    #pragma unroll
    for (int r = 0; r < RPT; ++r)
        qb[r] = *(const float4*)(qp + rbase + (long)r * DD);

    asm volatile("s_waitcnt vmcnt(0)" ::: "memory");
    __syncthreads();

    // ---- phase B: team totals from LDS ----
    const int tbase = (team * RPT) * DD + qd * 4;
    float4 tk = make_float4(0.f, 0.f, 0.f, 0.f);
    float4 tv = make_float4(0.f, 0.f, 0.f, 0.f);
    #pragma unroll
    for (int r = 0; r < RPT; ++r) {
        const float4 k4 = *(const float4*)&tileK[tbase + r * DD];
        const float4 v4 = *(const float4*)&tileV[tbase + r * DD];
        const float  m  = mv[r];
        const float kf0 = elu1(k4.x) * m;
        const float kf1 = elu1(k4.y) * m;
        const float kf2 = elu1(k4.z) * m;
        const float kf3 = elu1(k4.w) * m;
        tk.x += kf0;              tk.y += kf1;
        tk.z += kf2;              tk.w += kf3;
        tv.x += kf0 * (v4.x * m); tv.y += kf1 * (v4.y * m);
        tv.z += kf2 * (v4.z * m); tv.w += kf3 * (v4.w * m);
    }

    red[team][qd*4+0] = tk.x; red[team][qd*4+1] = tk.y;
    red[team][qd*4+2] = tk.z; red[team][qd*4+3] = tk.w;
    red[team][64+qd*4+0] = tv.x; red[team][64+qd*4+1] = tv.y;
    red[team][64+qd*4+2] = tv.z; red[team][64+qd*4+3] = tv.w;
    __syncthreads();

    // ---- in-place exclusive scan over the 16 teams ----
    if (t < RECF) {
        float acc = 0.f;
        #pragma unroll
        for (int i = 0; i < 16; ++i) {
            const float x = red[i][t];
            red[i][t] = acc;
            acc += x;
        }
    }
    __syncthreads();

    float4 rk, rv;
    rk.x = ck.x + red[team][qd*4+0]; rk.y = ck.y + red[team][qd*4+1];
    rk.z = ck.z + red[team][qd*4+2]; rk.w = ck.w + red[team][qd*4+3];
    rv.x = cv.x + red[team][64+qd*4+0]; rv.y = cv.y + red[team][64+qd*4+1];
    rv.z = cv.z + red[team][64+qd*4+2]; rv.w = cv.w + red[team][64+qd*4+3];

    // ---- phase C: serial scan over the team's 8 rows from LDS ----
    #pragma unroll
    for (int r = 0; r < RPT; ++r) {
        const float4 k4 = *(const float4*)&tileK[tbase + r * DD];
        const float4 v4 = *(const float4*)&tileV[tbase + r * DD];
        const float  m  = mv[r];
        const float kf0 = elu1(k4.x) * m;
        const float kf1 = elu1(k4.y) * m;
        const float kf2 = elu1(k4.z) * m;
        const float kf3 = elu1(k4.w) * m;
        rk.x += kf0;              rk.y += kf1;
        rk.z += kf2;              rk.w += kf3;
        rv.x += kf0 * (v4.x * m); rv.y += kf1 * (v4.y * m);
        rv.z += kf2 * (v4.z * m); rv.w += kf3 * (v4.w * m);

        float4 qf;
        qf.x = elu1(qb[r].x); qf.y = elu1(qb[r].y);
        qf.z = elu1(qb[r].z); qf.w = elu1(qb[r].w);

        float pz = qf.x*rk.x + qf.y*rk.y + qf.z*rk.z + qf.w*rk.w;
        pz = team_sum16(pz);

        const float z   = (pz + EPS) * m;
        const float inv = __builtin_amdgcn_rcpf(z);

        f32x4 o;
        o.x = qf.x * rv.x * inv;
        o.y = qf.y * rv.y * inv;
        o.z = qf.z * rv.z * inv;
        o.w = qf.w * rv.w * inv;
        __builtin_nontemporal_store(o, (f32x4*)(outp + rbase + (long)r * DD));
    }
}

} // namespace

extern "C" void kernel_launch(void* const* d_in, const int* in_sizes, int n_in,
                              void* d_out, int out_size, void* d_ws, size_t ws_size,
                              hipStream_t stream) {
    const float* q    = (const float*)d_in[0];
    const float* k    = (const float*)d_in[1];
    const float* v    = (const float*)d_in[2];
    const float* mask = (const float*)d_in[3];
    float* out = (float*)d_out;
    float* ws  = (float*)d_ws;   // needs BH*NCH*RECF floats = 1 MiB

    la_pass1<<<dim3(BH * NCH), dim3(256), 0, stream>>>(k, v, mask, ws);
    la_scan <<<dim3(BH),       dim3(RECF), 0, stream>>>(ws);
    la_pass2<<<dim3(BH * NCH), dim3(256), 0, stream>>>(q, k, v, mask, ws, out);
}